// Round 3
// baseline (635.609 us; speedup 1.0000x reference)
//
#include <hip/hip_runtime.h>
#include <hip/hip_bf16.h>

// Problem constants
#define B      64
#define CIN    3
#define HW     512
#define OW     128          // HW / 4
#define GN     16384        // OW*OW per-row gate elements
#define ROWS   64           // B * C_out(=1)
#define KSEL   4096         // top-k kept per row

#define SEL_T  1024         // threads per select block
#define EPT    16           // elements per thread (16*1024 = 16384)

typedef float floatv4 __attribute__((ext_vector_type(4)));

// ---------------------------------------------------------------------------
// Kernel 1: 4x4 stride-4 valid conv, 3->1 channels, f64 accumulation.
// One thread per output g element; 12 coalesced float4 loads per thread.
// f64 accumulation so the value ORDERING at the top-K boundary matches the
// harness's float64 numpy reference exactly (a boundary swap costs ~2e-3
// absmax > the 3.5e-4 threshold). Normal (cached) loads on purpose: mul
// re-reads `in`, and the 256 MB L3 can retain most of the 201 MB stream.
// ---------------------------------------------------------------------------
__global__ __launch_bounds__(256) void conv_kernel(
    const float* __restrict__ in, const float* __restrict__ w,
    double* __restrict__ g) {
  int f = blockIdx.x * 256 + threadIdx.x;       // 64*128*128 = 1,048,576
  int ox = f & 127;
  int oy = (f >> 7) & 127;
  int b  = f >> 14;

  const float4* inp = (const float4*)in;
  double acc = 0.0;
#pragma unroll
  for (int c = 0; c < CIN; ++c) {
#pragma unroll
    for (int ky = 0; ky < 4; ++ky) {
      int row = (b * CIN + c) * HW + (4 * oy + ky);
      float4 v = inp[row * (HW / 4) + ox];
      const float* wp = w + (c * 4 + ky) * 4;
      acc = fma((double)v.x, (double)wp[0], acc);
      acc = fma((double)v.y, (double)wp[1], acc);
      acc = fma((double)v.z, (double)wp[2], acc);
      acc = fma((double)v.w, (double)wp[3], acc);
    }
  }
  g[f] = acc;
}

// ---------------------------------------------------------------------------
// Kernel 2: exact per-row top-K via radix-select on the 64-bit monotone key.
// One block (1024 threads) per row; 16 keys/thread in registers. 12 bits/pass,
// <=6 passes, early exit when quota == bin count (typically pass 2). Suffix
// scan = wave shuffles + 16 wave totals: 2 barriers per pass. Exact-duplicate
// keys (never in practice) fall to an index-order rank path for correctness.
// ---------------------------------------------------------------------------
__global__ __launch_bounds__(1024) void select_kernel(
    const double* __restrict__ g, float* __restrict__ gsel) {
  const int r    = blockIdx.x;
  const int t    = threadIdx.x;
  const int lane = t & 63;
  const int wave = t >> 6;            // 0..15
  const size_t base = (size_t)r * GN;

  unsigned long long k[EPT];
#pragma unroll
  for (int j = 0; j < EPT; ++j) {
    double d = g[base + j * SEL_T + t];           // coalesced (stride-1 in t)
    unsigned long long u = (unsigned long long)__double_as_longlong(d);
    k[j] = (u >> 63) ? ~u : (u | 0x8000000000000000ULL);   // monotone map
  }

  __shared__ int hist[4096];
  __shared__ int wsum[16];
  __shared__ int sbin, sq, sm;
  __shared__ int smask[SEL_T];

  unsigned long long P = 0;   // selected prefix (bits above `shift`)
  int shift = 64;
  int q = KSEL;               // quota within current prefix class
  bool done = false;

  for (int pass = 0; pass < 6 && !done; ++pass) {
    const int sb = (pass < 5) ? 12 : 4;           // 12*5 + 4 = 64 bits
    shift -= sb;
    const int nb = 1 << sb;

    for (int i = t; i < nb; i += SEL_T) hist[i] = 0;
    __syncthreads();

#pragma unroll
    for (int j = 0; j < EPT; ++j) {
      bool match = (pass == 0) || ((k[j] >> (shift + sb)) == P);
      if (match) atomicAdd(&hist[(int)((k[j] >> shift) & (nb - 1))], 1);
    }
    __syncthreads();

    if (nb == 4096) {
      // each thread owns bins [4t, 4t+3]; higher t = higher bins
      int c0 = hist[4 * t], c1 = hist[4 * t + 1];
      int c2 = hist[4 * t + 2], c3 = hist[4 * t + 3];
      int s = c0 + c1 + c2 + c3;
      // wave inclusive suffix sum of chunk totals
      int v = s;
#pragma unroll
      for (int off = 1; off < 64; off <<= 1) {
        int u2 = __shfl_down(v, off, 64);
        if (lane + off < 64) v += u2;
      }
      if (lane == 0) wsum[wave] = v;              // wave total
      __syncthreads();
      int wave_above = 0;
      for (int w2 = wave + 1; w2 < 16; ++w2) wave_above += wsum[w2];
      int above = wave_above + (v - s);           // strictly above own chunk
      if (above < q && above + c3 >= q) { sbin = 4*t+3; sq = q - above; sm = c3; }
      above += c3;
      if (above < q && above + c2 >= q) { sbin = 4*t+2; sq = q - above; sm = c2; }
      above += c2;
      if (above < q && above + c1 >= q) { sbin = 4*t+1; sq = q - above; sm = c1; }
      above += c1;
      if (above < q && above + c0 >= q) { sbin = 4*t+0; sq = q - above; sm = c0; }
      __syncthreads();
    } else {                                      // nb == 16: trivial serial
      if (t == 0) {
        int above = 0;
        for (int bn = nb - 1; bn >= 0; --bn) {
          int c = hist[bn];
          if (above < q && above + c >= q) { sbin = bn; sq = q - above; sm = c; break; }
          above += c;
        }
      }
      __syncthreads();
    }

    P = (P << sb) | (unsigned long long)sbin;
    q = sq;
    if (sq == sm) done = true;                    // whole class selected
    __syncthreads();                              // guard sbin/sq/sm vs next pass
  }

  const bool need_rank = !done;                   // full 64-bit tie (pathological)
  if (need_rank) {
    int mask = 0;
#pragma unroll
    for (int j = 0; j < EPT; ++j) if (k[j] == P) mask |= (1 << j);
    smask[t] = mask;
    __syncthreads();
  }

#pragma unroll
  for (int j = 0; j < EPT; ++j) {
    bool sel;
    if (!need_rank) {
      sel = (k[j] >> shift) >= P;                 // >P selected earlier, ==P all in
    } else {
      if (k[j] > P)      sel = true;
      else if (k[j] < P) sel = false;
      else {
        int rk = 0;
        for (int t2 = 0; t2 < SEL_T; ++t2) {
          int m2 = smask[t2];
          rk += __popc(m2 & ((1 << j) - 1));
          if (t2 < t) rk += (m2 >> j) & 1;
        }
        sel = rk < q;
      }
    }
    unsigned long long kk = k[j];
    unsigned long long bits = (kk >> 63) ? (kk ^ 0x8000000000000000ULL) : ~kk;
    double d = __longlong_as_double((long long)bits);
    gsel[base + j * SEL_T + t] = sel ? (float)d : 0.0f;
  }
}

// ---------------------------------------------------------------------------
// Kernel 3: out = in * upsampled(gsel). 4 float4s (64 B) per thread, spanning
// exactly 4 gsel cells -> one vectorized gate load. Zero-skip per 16 B load
// (HW skips the full 64 B sector when all 4 gates are zero; ~32% of sectors
// at 25% gate density). Nontemporal in-loads and out-stores: `out` is never
// re-read and `in` won't be re-read after this — keep them from evicting
// useful L2/L3 lines.
// ---------------------------------------------------------------------------
__global__ __launch_bounds__(256) void mul_kernel(
    const floatv4* __restrict__ in, const floatv4* __restrict__ gsel4,
    floatv4* __restrict__ out) {
  unsigned tq = blockIdx.x * 256 + threadIdx.x;   // 3,145,728 threads
  unsigned q  = tq * 4;                           // base float4 index (aligned 4)
  unsigned x4 = q & 127;                          // x-quad 0..127 (multiple of 4)
  unsigned y  = (q >> 7) & 511;
  unsigned bc = q >> 16;                          // b*3 + c
  unsigned b  = bc / 3u;

  floatv4 s4 = gsel4[(b * GN + (y >> 2) * OW + x4) >> 2];
  float s[4] = {s4.x, s4.y, s4.z, s4.w};
#pragma unroll
  for (int i = 0; i < 4; ++i) {
    floatv4 o;
    float si = s[i];
    if (si != 0.0f) {
      floatv4 v = __builtin_nontemporal_load(&in[q + i]);
      o = v * si;
    } else {
      o = (floatv4)0.0f;
    }
    __builtin_nontemporal_store(o, &out[q + i]);
  }
}

extern "C" void kernel_launch(void* const* d_in, const int* in_sizes, int n_in,
                              void* d_out, int out_size, void* d_ws, size_t ws_size,
                              hipStream_t stream) {
  const float* in = (const float*)d_in[0];
  const float* w  = (const float*)d_in[1];
  float* out = (float*)d_out;

  double* g    = (double*)d_ws;                                  // 8 MB
  float*  gsel = (float*)((char*)d_ws + (size_t)ROWS * GN * 8);  // +4 MB

  conv_kernel<<<(B * OW * OW) / 256, 256, 0, stream>>>(in, w, g);
  select_kernel<<<ROWS, SEL_T, 0, stream>>>(g, gsel);
  mul_kernel<<<(B * CIN * HW * HW / 16) / 256, 256, 0, stream>>>(
      (const floatv4*)in, (const floatv4*)gsel, (floatv4*)out);
}

// Round 4
// 374.867 us; speedup vs baseline: 1.6956x; 1.6956x over previous
//
#include <hip/hip_runtime.h>
#include <hip/hip_bf16.h>

// Problem constants
#define B      64
#define CIN    3
#define HW     512
#define OW     128          // HW / 4
#define GN     16384        // OW*OW per-row gate elements
#define ROWS   64           // B * C_out(=1)
#define KSEL   4096         // top-k kept per row

#define SEL_T  1024         // threads per select block
#define EPT    16           // elements per thread (16*1024 = 16384)

// ---------------------------------------------------------------------------
// Kernel 1: 4x4 stride-4 valid conv, 3->1 channels, f64 accumulation.
// One thread per output g element; 12 coalesced float4 loads per thread.
// f64 accumulation so the value ORDERING at the top-K boundary matches the
// harness's float64 numpy reference exactly (a boundary swap costs ~2e-3
// absmax > the 3.5e-4 threshold). Cached loads on purpose: mul re-reads
// `in`, and the 256 MB L3 retains most of the 201 MB stream.
// ---------------------------------------------------------------------------
__global__ __launch_bounds__(256) void conv_kernel(
    const float* __restrict__ in, const float* __restrict__ w,
    double* __restrict__ g) {
  int f = blockIdx.x * 256 + threadIdx.x;       // 64*128*128 = 1,048,576
  int ox = f & 127;
  int oy = (f >> 7) & 127;
  int b  = f >> 14;

  const float4* inp = (const float4*)in;
  double acc = 0.0;
#pragma unroll
  for (int c = 0; c < CIN; ++c) {
#pragma unroll
    for (int ky = 0; ky < 4; ++ky) {
      int row = (b * CIN + c) * HW + (4 * oy + ky);
      float4 v = inp[row * (HW / 4) + ox];
      const float* wp = w + (c * 4 + ky) * 4;
      acc = fma((double)v.x, (double)wp[0], acc);
      acc = fma((double)v.y, (double)wp[1], acc);
      acc = fma((double)v.z, (double)wp[2], acc);
      acc = fma((double)v.w, (double)wp[3], acc);
    }
  }
  g[f] = acc;
}

// ---------------------------------------------------------------------------
// Kernel 2: exact per-row top-K via radix-select on the 64-bit monotone key.
// One block (1024 threads) per row; 16 keys/thread in registers. 12 bits/pass,
// <=6 passes, early exit when quota == bin count (typically pass 2). Suffix
// scan = wave shuffles + 16 wave totals: 2 barriers per pass. Exact-duplicate
// keys (never in practice) fall to an index-order rank path for correctness.
// ---------------------------------------------------------------------------
__global__ __launch_bounds__(1024) void select_kernel(
    const double* __restrict__ g, float* __restrict__ gsel) {
  const int r    = blockIdx.x;
  const int t    = threadIdx.x;
  const int lane = t & 63;
  const int wave = t >> 6;            // 0..15
  const size_t base = (size_t)r * GN;

  unsigned long long k[EPT];
#pragma unroll
  for (int j = 0; j < EPT; ++j) {
    double d = g[base + j * SEL_T + t];           // coalesced (stride-1 in t)
    unsigned long long u = (unsigned long long)__double_as_longlong(d);
    k[j] = (u >> 63) ? ~u : (u | 0x8000000000000000ULL);   // monotone map
  }

  __shared__ int hist[4096];
  __shared__ int wsum[16];
  __shared__ int sbin, sq, sm;
  __shared__ int smask[SEL_T];

  unsigned long long P = 0;   // selected prefix (bits above `shift`)
  int shift = 64;
  int q = KSEL;               // quota within current prefix class
  bool done = false;

  for (int pass = 0; pass < 6 && !done; ++pass) {
    const int sb = (pass < 5) ? 12 : 4;           // 12*5 + 4 = 64 bits
    shift -= sb;
    const int nb = 1 << sb;

    for (int i = t; i < nb; i += SEL_T) hist[i] = 0;
    __syncthreads();

#pragma unroll
    for (int j = 0; j < EPT; ++j) {
      bool match = (pass == 0) || ((k[j] >> (shift + sb)) == P);
      if (match) atomicAdd(&hist[(int)((k[j] >> shift) & (nb - 1))], 1);
    }
    __syncthreads();

    if (nb == 4096) {
      // each thread owns bins [4t, 4t+3]; higher t = higher bins
      int c0 = hist[4 * t], c1 = hist[4 * t + 1];
      int c2 = hist[4 * t + 2], c3 = hist[4 * t + 3];
      int s = c0 + c1 + c2 + c3;
      // wave inclusive suffix sum of chunk totals
      int v = s;
#pragma unroll
      for (int off = 1; off < 64; off <<= 1) {
        int u2 = __shfl_down(v, off, 64);
        if (lane + off < 64) v += u2;
      }
      if (lane == 0) wsum[wave] = v;              // wave total
      __syncthreads();
      int wave_above = 0;
      for (int w2 = wave + 1; w2 < 16; ++w2) wave_above += wsum[w2];
      int above = wave_above + (v - s);           // strictly above own chunk
      if (above < q && above + c3 >= q) { sbin = 4*t+3; sq = q - above; sm = c3; }
      above += c3;
      if (above < q && above + c2 >= q) { sbin = 4*t+2; sq = q - above; sm = c2; }
      above += c2;
      if (above < q && above + c1 >= q) { sbin = 4*t+1; sq = q - above; sm = c1; }
      above += c1;
      if (above < q && above + c0 >= q) { sbin = 4*t+0; sq = q - above; sm = c0; }
      __syncthreads();
    } else {                                      // nb == 16: trivial serial
      if (t == 0) {
        int above = 0;
        for (int bn = nb - 1; bn >= 0; --bn) {
          int c = hist[bn];
          if (above < q && above + c >= q) { sbin = bn; sq = q - above; sm = c; break; }
          above += c;
        }
      }
      __syncthreads();
    }

    P = (P << sb) | (unsigned long long)sbin;
    q = sq;
    if (sq == sm) done = true;                    // whole class selected
    __syncthreads();                              // guard sbin/sq/sm vs next pass
  }

  const bool need_rank = !done;                   // full 64-bit tie (pathological)
  if (need_rank) {
    int mask = 0;
#pragma unroll
    for (int j = 0; j < EPT; ++j) if (k[j] == P) mask |= (1 << j);
    smask[t] = mask;
    __syncthreads();
  }

#pragma unroll
  for (int j = 0; j < EPT; ++j) {
    bool sel;
    if (!need_rank) {
      sel = (k[j] >> shift) >= P;                 // >P selected earlier, ==P all in
    } else {
      if (k[j] > P)      sel = true;
      else if (k[j] < P) sel = false;
      else {
        int rk = 0;
        for (int t2 = 0; t2 < SEL_T; ++t2) {
          int m2 = smask[t2];
          rk += __popc(m2 & ((1 << j) - 1));
          if (t2 < t) rk += (m2 >> j) & 1;
        }
        sel = rk < q;
      }
    }
    unsigned long long kk = k[j];
    unsigned long long bits = (kk >> 63) ? (kk ^ 0x8000000000000000ULL) : ~kk;
    double d = __longlong_as_double((long long)bits);
    gsel[base + j * SEL_T + t] = sel ? (float)d : 0.0f;
  }
}

// ---------------------------------------------------------------------------
// Kernel 3: out = in * upsampled(gsel). One float4 per thread — a wave spans
// a contiguous 1 KB (fully coalesced loads AND stores; full-line writes so L2
// write-combining works, no RMW amplification). 75% of gates are zero: skip
// the input load there (exec-masked; a fully-zero gsel cell skips its 64 B
// line entirely). Cached (non-NT) loads so the L3-resident `in` from conv is
// reused. [Round-3 lesson: NT partial-line stores doubled WRITE_SIZE; the
// 64 B/thread layout uncoalesced every access — 330 us vs ~60 us.]
// ---------------------------------------------------------------------------
__global__ __launch_bounds__(256) void mul_kernel(
    const float4* __restrict__ in, const float* __restrict__ gsel,
    float4* __restrict__ out) {
  unsigned f = blockIdx.x * 256 + threadIdx.x;  // 12,582,912 float4s
  unsigned x4 = f & 127;                        // = ox (x/4)
  unsigned y  = (f >> 7) & 511;
  unsigned bc = f >> 16;                        // b*3 + c
  unsigned b  = bc / 3u;
  float s = gsel[b * GN + (y >> 2) * OW + x4];
  float4 o;
  if (s != 0.0f) {
    float4 v = in[f];
    o.x = v.x * s; o.y = v.y * s; o.z = v.z * s; o.w = v.w * s;
  } else {
    o.x = 0.0f; o.y = 0.0f; o.z = 0.0f; o.w = 0.0f;
  }
  out[f] = o;
}

extern "C" void kernel_launch(void* const* d_in, const int* in_sizes, int n_in,
                              void* d_out, int out_size, void* d_ws, size_t ws_size,
                              hipStream_t stream) {
  const float* in = (const float*)d_in[0];
  const float* w  = (const float*)d_in[1];
  float* out = (float*)d_out;

  double* g    = (double*)d_ws;                                  // 8 MB
  float*  gsel = (float*)((char*)d_ws + (size_t)ROWS * GN * 8);  // +4 MB

  conv_kernel<<<(B * OW * OW) / 256, 256, 0, stream>>>(in, w, g);
  select_kernel<<<ROWS, SEL_T, 0, stream>>>(g, gsel);
  mul_kernel<<<(B * CIN * HW * HW / 4) / 256, 256, 0, stream>>>(
      (const float4*)in, gsel, (float4*)out);
}